// Round 8
// baseline (128.634 us; speedup 1.0000x reference)
//
#include <hip/hip_runtime.h>
#include <math.h>

// B=2048, L=64. out = sum(kl) + (BETA-1)*mean_i(log_qz_i - log_qz_product_i)
// lp2[i,j,l] = lp/ln2 = a2*d^2 + b2, d = z_i_l - m_j_l, a2 = -0.5/ln2*exp(-lv) < 0
// Single-pass LSE with constant shift BVAL (valid since lp2 <= b2 << BVAL).
// Horner: lp2 - BVAL = fma(fma(z, a2, c1), z, c0'), c1=-2*a2*m, c0'=a2*m^2+b2-BVAL.
//
// Round-8: r6 baseline (best: k23=69.4us; r7 unroll-8 reverted, was null).
// ONE change: PARITY PHASE ORDER. All 8 blocks/CU start near-simultaneously,
// so K2 (VALU-saturated ~25us, trans idle) and K3 (trans-saturated ~45us,
// VALU ~75%) run in cross-block lockstep -> sequential phase maxima = 70us.
// Odd i-tile blocks now run K3-then-K2 -> each CU co-hosts both phases at all
// times; floor becomes max(total VALU, total trans) ~ 59us. Same grid, same
// per-block work, same barriers, same values & reduction order -> bit-identical.

#define NB 2048
#define NL 64
#define NE (NB * NL)
#define BVAL 12.0f

__device__ __forceinline__ float wredsum(float v) {
#pragma unroll
  for (int o = 32; o; o >>= 1) v += __shfl_xor(v, o, 64);
  return v;
}
__device__ __forceinline__ float wredmax(float v) {
#pragma unroll
  for (int o = 32; o; o >>= 1) v = fmaxf(v, __shfl_xor(v, o, 64));
  return v;
}

// K1: packed Horner coeffs (a2,c1,c0',0) for the K3 path, interleaved (a2,c1)
// transposed array + qc2 for the K2 path, per-block kl partial sums.
__global__ __launch_bounds__(256) void k1_pre(const float* __restrict__ kl,
                                              const float* __restrict__ zm,
                                              const float* __restrict__ zlv,
                                              float4* __restrict__ PK2,
                                              float2* __restrict__ AM2T,
                                              float* __restrict__ QC2,
                                              float* __restrict__ KLP) {
  const float INVLN2 = 1.4426950408889634f;
  const float LOG2PI = 1.8378770664093453f;
  int tid = threadIdx.x;
  int e = blockIdx.x * 256 + tid;  // < NE
  int j = e >> 6, l = e & 63;
  float lv = zlv[e], m = zm[e];
  float a2 = -0.5f * INVLN2 * __expf(-lv);
  float b2 = -0.5f * INVLN2 * (lv + LOG2PI);
  float c1 = -2.0f * a2 * m;
  float c0 = fmaf(a2 * m, m, b2);  // true a2*m^2 + b2
  PK2[e] = make_float4(a2, c1, c0 - BVAL, 0.0f);
  AM2T[l * NB + j] = make_float2(a2, c1);
  float q = wredsum(c0);  // sum_l (a2 m^2 + b2) for this j (one j per wave)
  if (l == 0) QC2[j] = q;
  float ks = wredsum(kl[e]);
  __shared__ float sk[4];
  if (l == 0) sk[tid >> 6] = ks;
  __syncthreads();
  if (tid == 0) KLP[blockIdx.x] = sk[0] + sk[1] + sk[2] + sk[3];
}

// Fused K2+K3, parity phase order. grid (8 j-chunks, 256 i-tiles), 256 thr.
// K2 phase: thread = one j, 8 i's; z and z^2 tiles staged in LDS.
// K3 phase: thread = (wave w, lane l); 64 j's per wave, 8 i's per thread.
// blockIdx.y & 1 selects phase order (K2K3 vs K3K2) -> cross-block pipe mix.
// Linear block id = jc + 8*it -> XCD = bid%8 = jc: each XCD streams only its
// own jc-chunk of PK2/AM2T (L2 locality); keep this mapping.
__global__ __launch_bounds__(256) void k23(const float* __restrict__ zs,
                                           const float2* __restrict__ AM2T,
                                           const float* __restrict__ QC2,
                                           const float4* __restrict__ PK2,
                                           float* __restrict__ TPM,
                                           float* __restrict__ TPS,
                                           float* __restrict__ SP) {
  int jc = blockIdx.x;      // 0..7
  int i0 = blockIdx.y * 8;  // i tile base
  int tid = threadIdx.x;
  int w = tid >> 6, l = tid & 63;
  int j = jc * 256 + tid;

  __shared__ float zsh[64][8];  // [k][r]  z
  __shared__ float zqh[64][8];  // [k][r]  z^2 (same rounding as in-loop z*z)
  __shared__ float lm[4][8], ls[4][8];
  __shared__ float lss[4][8][64];

  if (tid < 128) {
    int k = tid >> 1, r0 = (tid & 1) * 4;
#pragma unroll
    for (int r = 0; r < 4; ++r) {
      float z = zs[(i0 + r0 + r) * NL + k];
      zsh[k][r0 + r] = z;
      zqh[k][r0 + r] = z * z;
    }
  }
  __syncthreads();

  // ---------------- K2 phase (identical math/order to r6) ----------------
  auto K2phase = [&]() {
    float accv[8];
    float q = QC2[j];
#pragma unroll
    for (int r = 0; r < 8; ++r) accv[r] = q;
    for (int k = 0; k < 64; ++k) {
      float2 am = AM2T[k * NB + j];                  // (a2, c1) per-thread
      const float4* z4 = (const float4*)&zsh[k][0];  // wave-uniform -> bcast
      const float4* q4 = (const float4*)&zqh[k][0];
      float4 za = z4[0], zb = z4[1];
      float4 qa = q4[0], qb = q4[1];
      float zk[8] = {za.x, za.y, za.z, za.w, zb.x, zb.y, zb.z, zb.w};
      float zz[8] = {qa.x, qa.y, qa.z, qa.w, qb.x, qb.y, qb.z, qb.w};
#pragma unroll
      for (int r = 0; r < 8; ++r) {
        accv[r] = fmaf(zz[r], am.x, accv[r]);  // == fmaf(zk*zk, a2, acc)
        accv[r] = fmaf(zk[r], am.y, accv[r]);  // == fmaf(zk,    c1, acc)
      }
    }
    float Mt[8];
#pragma unroll
    for (int r = 0; r < 8; ++r) {
      float mx = wredmax(accv[r]);
      if (l == 0) lm[w][r] = mx;
    }
    __syncthreads();
#pragma unroll
    for (int r = 0; r < 8; ++r)
      Mt[r] = fmaxf(fmaxf(lm[0][r], lm[1][r]), fmaxf(lm[2][r], lm[3][r]));
#pragma unroll
    for (int r = 0; r < 8; ++r) {
      float ss = wredsum(__builtin_amdgcn_exp2f(accv[r] - Mt[r]));
      if (l == 0) ls[w][r] = ss;
    }
    __syncthreads();
    if (tid == 0) {
#pragma unroll
      for (int r = 0; r < 8; ++r) {
        TPM[(i0 + r) * 8 + jc] = Mt[r];
        TPS[(i0 + r) * 8 + jc] = ls[0][r] + ls[1][r] + ls[2][r] + ls[3][r];
      }
    }
  };

  // ---------------- K3 phase (identical math/order to r6) ----------------
  auto K3phase = [&]() {
    float zr[8];
#pragma unroll
    for (int r = 0; r < 8; ++r) zr[r] = zs[(i0 + r) * NL + l];
    float S[8];
#pragma unroll
    for (int r = 0; r < 8; ++r) S[r] = 0.0f;
    const float4* p = PK2 + (size_t)(jc * 256 + w * 64) * NL + l;
#pragma unroll 4
    for (int jj = 0; jj < 64; ++jj) {
      float4 c = p[(size_t)jj * NL];
#pragma unroll
      for (int r = 0; r < 8; ++r) {
        float lp2 = fmaf(fmaf(zr[r], c.x, c.y), zr[r], c.z);
        S[r] += __builtin_amdgcn_exp2f(lp2);
      }
    }
#pragma unroll
    for (int r = 0; r < 8; ++r) lss[w][r][l] = S[r];
    __syncthreads();
    for (int pp = tid; pp < 512; pp += 256) {
      int r = pp >> 6, ll = pp & 63;
      float Sc = lss[0][r][ll] + lss[1][r][ll] + lss[2][r][ll] + lss[3][r][ll];
      SP[((size_t)jc * NB + (i0 + r)) * NL + ll] = Sc;
    }
    __syncthreads();  // lss stable before any later phase reuses LDS space
  };

  if ((blockIdx.y & 1) == 0) {
    K2phase();
    K3phase();
  } else {
    K3phase();
    K2phase();
  }
}

// K4: per-i: sum 8 j-chunk partials per (i,l) -> log2, sum over l (+64*BVAL),
// LSE-merge the 8 t-chunks -> log_qz; write per-i contribution. 1 wave per i.
__global__ __launch_bounds__(256) void k4_fin(const float* __restrict__ SP,
                                              const float* __restrict__ TPM,
                                              const float* __restrict__ TPS,
                                              float* __restrict__ PERI) {
  int tid = threadIdx.x;
  int w = tid >> 6, l = tid & 63;
  int i = blockIdx.x * 4 + w;
  float S = 0.0f;
#pragma unroll
  for (int s = 0; s < 8; ++s) S += SP[((size_t)s * NB + i) * NL + l];
  float val = __builtin_amdgcn_logf(S);  // log2
  float lqp2 = wredsum(val) + 64.0f * BVAL;
  float tm = (l < 8) ? TPM[i * 8 + l] : -1e30f;
  float ts = (l < 8) ? TPS[i * 8 + l] : 0.0f;
  float Mt = wredmax(tm);
  float St = wredsum(ts * __builtin_amdgcn_exp2f(tm - Mt));
  float lqz2 = Mt + __builtin_amdgcn_logf(St);
  if (l == 0) PERI[i] = lqz2 - lqp2;
}

// K5: final scalar. sum KLP[512], sum PERI[2048].
__global__ __launch_bounds__(256) void k5_out(const float* __restrict__ KLP,
                                              const float* __restrict__ PERI,
                                              float* __restrict__ out) {
  int tid = threadIdx.x;
  float a = 0.0f, b = 0.0f;
  for (int x = tid; x < 512; x += 256) a += KLP[x];
  for (int x = tid; x < 2048; x += 256) b += PERI[x];
  float ra = wredsum(a), rb = wredsum(b);
  __shared__ float sa[4], sb[4];
  if ((tid & 63) == 0) {
    sa[tid >> 6] = ra;
    sb[tid >> 6] = rb;
  }
  __syncthreads();
  if (tid == 0) {
    const float LN2 = 0.6931471805599453f;
    float ka = sa[0] + sa[1] + sa[2] + sa[3];
    float kb = sb[0] + sb[1] + sb[2] + sb[3];
    out[0] = ka + 5.0f * LN2 * kb * (1.0f / (float)NB);
  }
}

extern "C" void kernel_launch(void* const* d_in, const int* in_sizes, int n_in,
                              void* d_out, int out_size, void* d_ws, size_t ws_size,
                              hipStream_t stream) {
  const float* kl = (const float*)d_in[0];
  const float* zm = (const float*)d_in[1];
  const float* zlv = (const float*)d_in[2];
  const float* zs = (const float*)d_in[3];
  float* ws = (float*)d_ws;

  float* PK2 = ws;                  // 4*NE
  float* AM2T = PK2 + 4 * NE;       // 2*NE (interleaved a2,c1 transposed)
  float* QC2 = AM2T + 2 * NE;       // NB
  float* SP = QC2 + NB;             // 8*NE
  float* TPM = SP + 8 * NE;         // NB*8
  float* TPS = TPM + NB * 8;        // NB*8
  float* KLP = TPS + NB * 8;        // 512
  float* PERI = KLP + 512;          // NB     (total ~7.3 MB)

  k1_pre<<<NE / 256, 256, 0, stream>>>(kl, zm, zlv, (float4*)PK2,
                                       (float2*)AM2T, QC2, KLP);
  k23<<<dim3(8, NB / 8), 256, 0, stream>>>(zs, (const float2*)AM2T, QC2,
                                           (const float4*)PK2, TPM, TPS, SP);
  k4_fin<<<NB / 4, 256, 0, stream>>>(SP, TPM, TPS, PERI);
  k5_out<<<1, 256, 0, stream>>>(KLP, PERI, (float*)d_out);
}